// Round 4
// baseline (325.412 us; speedup 1.0000x reference)
//
#include <hip/hip_runtime.h>
#include <hip/hip_bf16.h>

#define NSP 4096   // H*W
#define CCH 256    // C
#define CIN 128    // Ci
#define BN_EPS 1e-5f

typedef __bf16 bf16x8 __attribute__((ext_vector_type(8)));
typedef __bf16 bf16x4 __attribute__((ext_vector_type(4)));
typedef float f32x4 __attribute__((ext_vector_type(4)));

// ================= fp32 tile helpers (prep/chainA/chainB) ========================

__device__ __forceinline__ float4 fetch_tr(const float* __restrict__ A, int lda, int m0,
                                           int k0, int tid) {
  const int r = tid >> 2, kq = (tid & 3) << 2;
  return *(const float4*)(A + (size_t)(m0 + r) * lda + k0 + kq);
}
__device__ __forceinline__ void stash_tr(float (*As)[68], float4 v, int tid) {
  const int r = tid >> 2, kq = (tid & 3) << 2;
  As[kq + 0][r] = v.x; As[kq + 1][r] = v.y; As[kq + 2][r] = v.z; As[kq + 3][r] = v.w;
}
__device__ __forceinline__ float4 fetch_dir(const float* __restrict__ B, int ldb, int k0,
                                            int n0, int tid) {
  const int kr = tid >> 4, nq = (tid & 15) << 2;
  return *(const float4*)(B + (size_t)(k0 + kr) * ldb + n0 + nq);
}
__device__ __forceinline__ void stash_dir(float (*Bs)[68], float4 v, int tid) {
  const int kr = tid >> 4, nq = (tid & 15) << 2;
  *(float4*)(&Bs[kr][nq]) = v;
}

__device__ __forceinline__ void mm16(const float (*As)[68], const float (*Bs)[68],
                                     float acc[4][4], int ty, int tx) {
#pragma unroll
  for (int kk = 0; kk < 16; ++kk) {
    const float4 av = *(const float4*)(&As[kk][ty << 2]);
    const float4 bv = *(const float4*)(&Bs[kk][tx << 2]);
    const float ar[4] = {av.x, av.y, av.z, av.w};
    const float br[4] = {bv.x, bv.y, bv.z, bv.w};
#pragma unroll
    for (int i = 0; i < 4; ++i)
#pragma unroll
      for (int j = 0; j < 4; ++j) acc[i][j] += ar[i] * br[j];
  }
}

__device__ __forceinline__ void store_tile(float* __restrict__ C, int ldc, int m0, int n0,
                                           const float acc[4][4], int ty, int tx) {
#pragma unroll
  for (int i = 0; i < 4; ++i) {
    const float4 v = make_float4(acc[i][0], acc[i][1], acc[i][2], acc[i][3]);
    *(float4*)(C + (size_t)(m0 + (ty << 2) + i) * ldc + n0 + (tx << 2)) = v;
  }
}

__device__ __forceinline__ float wave_reduce(float v) {
#pragma unroll
  for (int off = 32; off; off >>= 1) v += __shfl_down(v, off);
  return v;  // valid in lane 0
}

// ================= setup: cast_b (0..1023) + prep (1024..1055) + cast_a (1056..2079)
__global__ __launch_bounds__(256) void setup_kernel(
    const float* __restrict__ bin, __bf16* __restrict__ bhi, __bf16* __restrict__ blo,
    float* __restrict__ srow, const float* __restrict__ W_w, const float* __restrict__ g_w,
    const float* __restrict__ phi_w, const float* __restrict__ theta_w,
    float* __restrict__ Wg, float* __restrict__ PT,
    const float* __restrict__ a, __bf16* __restrict__ at) {
  __shared__ float smem[64 * 68];
  const int idx = blockIdx.x;
  const int t = threadIdx.x;
  if (idx < 1024) {
    // ---- cast b row -> bf16 hi/lo + exact fp32 row sum ----
    const int row = idx;
    const float* src = bin + (size_t)row * NSP + t * 16;
    float sum = 0.f;
    __bf16 hi[16], lo[16];
#pragma unroll
    for (int i = 0; i < 4; ++i) {
      const float4 v = *(const float4*)(src + i * 4);
      const float vv[4] = {v.x, v.y, v.z, v.w};
#pragma unroll
      for (int j = 0; j < 4; ++j) {
        const float x = vv[j];
        sum += x;
        const __bf16 h = (__bf16)x;
        hi[i * 4 + j] = h;
        lo[i * 4 + j] = (__bf16)(x - (float)h);
      }
    }
    __bf16* dh = bhi + (size_t)row * NSP + t * 16;
    __bf16* dl = blo + (size_t)row * NSP + t * 16;
    *(bf16x8*)dh = *(bf16x8*)&hi[0];
    *(bf16x8*)(dh + 8) = *(bf16x8*)&hi[8];
    *(bf16x8*)dl = *(bf16x8*)&lo[0];
    *(bf16x8*)(dl + 8) = *(bf16x8*)&lo[8];
#pragma unroll
    for (int off = 32; off; off >>= 1) sum += __shfl_down(sum, off);
    if ((t & 63) == 0) smem[t >> 6] = sum;
    __syncthreads();
    if (t == 0) srow[row] = smem[0] + smem[1] + smem[2] + smem[3];
  } else if (idx < 1056) {
    // ---- prep: Wg = W_w @ g_w (z=0) ; PT = phi_w^T @ theta_w (z=1) ----
    const int p = idx - 1024;
    const int zsel = p >> 4, rem = p & 15;
    const int m0 = (rem >> 2) * 64, n0 = (rem & 3) * 64;
    float (*As)[68] = (float(*)[68])smem;
    float (*Bs)[68] = (float(*)[68])(smem + 16 * 68);
    const int ty = t >> 4, tx = t & 15;
    float acc[4][4] = {};
    if (zsel == 0) {
      float4 ar = fetch_tr(W_w, CIN, m0, 0, t);
      float4 br = fetch_dir(g_w, CCH, 0, n0, t);
      for (int kt = 0; kt < 8; ++kt) {
        stash_tr(As, ar, t); stash_dir(Bs, br, t);
        __syncthreads();
        if (kt < 7) { ar = fetch_tr(W_w, CIN, m0, (kt + 1) * 16, t);
                      br = fetch_dir(g_w, CCH, (kt + 1) * 16, n0, t); }
        mm16(As, Bs, acc, ty, tx);
        __syncthreads();
      }
      store_tile(Wg, 256, m0, n0, acc, ty, tx);
    } else {
      float4 ar = fetch_dir(phi_w, CCH, 0, m0, t);
      float4 br = fetch_dir(theta_w, CCH, 0, n0, t);
      for (int kt = 0; kt < 8; ++kt) {
        stash_dir(As, ar, t); stash_dir(Bs, br, t);
        __syncthreads();
        if (kt < 7) { ar = fetch_dir(phi_w, CCH, (kt + 1) * 16, m0, t);
                      br = fetch_dir(theta_w, CCH, (kt + 1) * 16, n0, t); }
        mm16(As, Bs, acc, ty, tx);
        __syncthreads();
      }
      store_tile(PT, 256, m0, n0, acc, ty, tx);
    }
  } else {
    // ---- cast a -> bf16 transposed: at[b][n][c] ----
    const int p = idx - 1056;
    const int n0 = (p & 63) * 64, c0 = ((p >> 6) & 3) * 64, b = p >> 8;
    float (*tile)[68] = (float(*)[68])smem;
    const int cr = t >> 4, nq = (t & 15) << 2;
    const float* src = a + ((size_t)(b * CCH + c0)) * NSP + n0;
#pragma unroll
    for (int s = 0; s < 4; ++s) {
      const float4 v = *(const float4*)(src + (size_t)(cr + s * 16) * NSP + nq);
      *(float4*)&tile[cr + s * 16][nq] = v;
    }
    __syncthreads();
    const int n = t >> 2, cq = (t & 3) << 4;
    __bf16 outv[16];
#pragma unroll
    for (int i = 0; i < 16; ++i) outv[i] = (__bf16)tile[cq + i][n];
    __bf16* dst = at + ((size_t)(b * NSP + n0 + n)) * CCH + c0 + cq;
    *(bf16x8*)dst = *(bf16x8*)&outv[0];
    *(bf16x8*)(dst + 8) = *(bf16x8*)&outv[8];
  }
}

// ================= gram (blocks 0..2047, K-split 32) + auxA (2048..2052) ========
__global__ __launch_bounds__(256) void gram_aux_kernel(
    const __bf16* __restrict__ bhi, const __bf16* __restrict__ blo,
    float* __restrict__ G, const float* __restrict__ srow,
    const float* __restrict__ W_w, const float* __restrict__ g_w,
    const float* __restrict__ phi_w, const float* __restrict__ theta_w,
    const float* __restrict__ theta_b, const float* __restrict__ phi_b,
    const float* __restrict__ g_b,
    float* __restrict__ Wgs, float* __restrict__ sPTv, float* __restrict__ wgb,
    float* __restrict__ vpt, float* __restrict__ vb_g, float* __restrict__ sg_g,
    float* __restrict__ dvec) {
  const int blk = blockIdx.x;
  const int t = threadIdx.x;
  const int wave = t >> 6, lane = t & 63;
  if (blk < 2048) {
    // ---- G[b] += Bhi*Bhi^T + Bhi*Blo^T + Blo*Bhi^T over K-chunk of 128 ----
    const int jt = blk & 3, it = (blk >> 2) & 3;
    const int z = blk >> 4;                 // 0..127
    const int batch = z >> 5, kc = z & 31;  // kc: 32 chunks of K=128
    const int m = lane & 15, q = lane >> 4;
    const size_t base = (size_t)batch * CCH * NSP;
    const size_t arow = base + (size_t)(it * 64 + wave * 16 + m) * NSP + kc * 128 + q * 8;
    const size_t brow = base + (size_t)(jt * 64 + m) * NSP + kc * 128 + q * 8;
    f32x4 acc[4] = {};
#pragma unroll
    for (int ks = 0; ks < 4; ++ks) {
      const int k = ks * 32;
      const bf16x8 ah = *(const bf16x8*)(bhi + arow + k);
      const bf16x8 al = *(const bf16x8*)(blo + arow + k);
#pragma unroll
      for (int t4 = 0; t4 < 4; ++t4) {
        const size_t boff = brow + (size_t)t4 * 16 * NSP + k;
        const bf16x8 bh = *(const bf16x8*)(bhi + boff);
        const bf16x8 bl = *(const bf16x8*)(blo + boff);
        acc[t4] = __builtin_amdgcn_mfma_f32_16x16x32_bf16(ah, bh, acc[t4], 0, 0, 0);
        acc[t4] = __builtin_amdgcn_mfma_f32_16x16x32_bf16(ah, bl, acc[t4], 0, 0, 0);
        acc[t4] = __builtin_amdgcn_mfma_f32_16x16x32_bf16(al, bh, acc[t4], 0, 0, 0);
      }
    }
    float* Gb = G + (size_t)batch * 65536;
#pragma unroll
    for (int t4 = 0; t4 < 4; ++t4)
#pragma unroll
      for (int r = 0; r < 4; ++r)
        atomicAdd(&Gb[(size_t)(it * 64 + wave * 16 + q * 4 + r) * 256 +
                      jt * 64 + t4 * 16 + m],
                  acc[t4][r]);
  } else if (blk < 2052) {
    // ---- auxA per-batch: sp = phi_w@s, sg = g_w@s -> Wgs, sPTv, d2, sg_g ----
    const int b = blk - 2048;
    __shared__ float sm[512];
    float* s_s = sm; float* sp_s = sm + 256; float* sg_s = sm + 384;
    s_s[t] = srow[b * 256 + t];
    __syncthreads();
    const float4 sv = *(const float4*)&s_s[lane * 4];
    for (int j = wave; j < 256; j += 4) {
      const float* row = (j < 128) ? (phi_w + (size_t)j * 256)
                                   : (g_w + (size_t)(j - 128) * 256);
      const float4 r = *(const float4*)(row + lane * 4);
      float v = fmaf(r.x, sv.x, fmaf(r.y, sv.y, fmaf(r.z, sv.z, r.w * sv.w)));
      v = wave_reduce(v);
      if (lane == 0) { if (j < 128) sp_s[j] = v; else sg_s[j - 128] = v; }
    }
    __syncthreads();
    if (t < 128) sg_g[b * 128 + t] = sg_s[t];
    {  // sPTv[c] = sum_i sp[i]*theta_w[i][c] (coalesced cols)
      float acc = 0.f;
#pragma unroll 8
      for (int i = 0; i < 128; ++i) acc += sp_s[i] * theta_w[(size_t)i * 256 + t];
      sPTv[b * 256 + t] = acc;
    }
    if (wave == 0) {  // d2 = sp . theta_b
      float pv = sp_s[lane] * theta_b[lane] + sp_s[lane + 64] * theta_b[lane + 64];
      pv = wave_reduce(pv);
      if (lane == 0) dvec[1 + b] = pv;
    }
    {  // Wgs[o] = W_w[o] . sg
      const float2 mv = *(const float2*)&sg_s[lane * 2];
      for (int o = wave; o < 256; o += 4) {
        const float2 r = *(const float2*)(W_w + (size_t)o * 128 + lane * 2);
        float v = fmaf(r.x, mv.x, r.y * mv.y);
        v = wave_reduce(v);
        if (lane == 0) Wgs[b * 256 + o] = v;
      }
    }
  } else {
    // ---- auxA global: vpt, vb, wgb, d1 ----
    __shared__ float sm2[384];
    float* pb_s = sm2; float* tb_s = sm2 + 128; float* gb_s = sm2 + 256;
    if (t < 128) { pb_s[t] = phi_b[t]; tb_s[t] = theta_b[t]; gb_s[t] = g_b[t]; }
    __syncthreads();
    {  // vpt[c] = sum_i phi_b[i]*theta_w[i][c]
      float acc = 0.f;
#pragma unroll 8
      for (int i = 0; i < 128; ++i) acc += pb_s[i] * theta_w[(size_t)i * 256 + t];
      vpt[t] = acc;
    }
    {  // vb[c] = sum_i phi_w[i][c]*theta_b[i]
      float acc = 0.f;
#pragma unroll 8
      for (int i = 0; i < 128; ++i) acc += phi_w[(size_t)i * 256 + t] * tb_s[i];
      vb_g[t] = acc;
    }
    if (wave == 0) {  // d1 = phi_b . theta_b
      float pv = pb_s[lane] * tb_s[lane] + pb_s[lane + 64] * tb_s[lane + 64];
      pv = wave_reduce(pv);
      if (lane == 0) dvec[0] = pv;
    }
    {  // wgb[o] = W_w[o] . g_b
      const float2 gv = *(const float2*)&gb_s[lane * 2];
      for (int o = wave; o < 256; o += 4) {
        const float2 r = *(const float2*)(W_w + (size_t)o * 128 + lane * 2);
        float v = fmaf(r.x, gv.x, r.y * gv.y);
        v = wave_reduce(v);
        if (lane == 0) wgb[o] = v;
      }
    }
  }
}

// ================= T1[b] = Wg @ G[b] (fp32 tiles, reg-prefetch) ==================
__global__ __launch_bounds__(256) void chainA_kernel(const float* __restrict__ Wg,
                                                     const float* __restrict__ G,
                                                     float* __restrict__ T1) {
  const int b = blockIdx.z;
  __shared__ float As[16][68], Bs[16][68];
  const int n0 = blockIdx.x * 64, m0 = blockIdx.y * 64;
  const int tx = threadIdx.x, ty = threadIdx.y;
  const int tid = (ty << 4) | tx;
  const float* Gb = G + (size_t)b * 65536;
  float acc[4][4] = {};
  float4 ar = fetch_tr(Wg, 256, m0, 0, tid);
  float4 br = fetch_dir(Gb, 256, 0, n0, tid);
  for (int kt = 0; kt < 16; ++kt) {
    stash_tr(As, ar, tid); stash_dir(Bs, br, tid);
    __syncthreads();
    if (kt < 15) { ar = fetch_tr(Wg, 256, m0, (kt + 1) * 16, tid);
                   br = fetch_dir(Gb, 256, (kt + 1) * 16, n0, tid); }
    mm16(As, Bs, acc, ty, tx);
    __syncthreads();
  }
  store_tile(T1 + (size_t)b * 65536, 256, m0, n0, acc, ty, tx);
}

// ================= chainB (blocks 0..63) + auxB (64..67) =========================
__global__ __launch_bounds__(256) void chainB_aux_kernel(
    const float* __restrict__ T1, const float* __restrict__ PT,
    const float* __restrict__ Wgs, const float* __restrict__ sPT,
    const float* __restrict__ wgb, const float* __restrict__ vpt,
    const float* __restrict__ G, const float* __restrict__ vb_g,
    const float* __restrict__ sg_g, const float* __restrict__ dvec,
    const float* __restrict__ g_w, const float* __restrict__ g_b,
    const float* __restrict__ W_w,
    const float* __restrict__ bn_gamma, const float* __restrict__ bn_beta,
    const float* __restrict__ bn_mean, const float* __restrict__ bn_var,
    __bf16* __restrict__ Whi, __bf16* __restrict__ Wlo,
    float* __restrict__ bias_out) {
  const int blk = blockIdx.x;
  const int t = threadIdx.x;
  const int wave = t >> 6, lane = t & 63;
  if (blk < 64) {
    // ---- W_out[b] (bf16 hi/lo) = scale*((T1@PT + rank1)/N + rank1') ----
    __shared__ float As[16][68], Bs[16][68];
    const int b = blk >> 4, m0 = ((blk >> 2) & 3) * 64, n0 = (blk & 3) * 64;
    const int ty = t >> 4, tx = t & 15;
    const float* T1b = T1 + (size_t)b * 65536;
    float acc[4][4] = {};
    float4 ar = fetch_tr(T1b, 256, m0, 0, t);
    float4 br = fetch_dir(PT, 256, 0, n0, t);
    for (int kt = 0; kt < 16; ++kt) {
      stash_tr(As, ar, t); stash_dir(Bs, br, t);
      __syncthreads();
      if (kt < 15) { ar = fetch_tr(T1b, 256, m0, (kt + 1) * 16, t);
                     br = fetch_dir(PT, 256, (kt + 1) * 16, n0, t); }
      mm16(As, Bs, acc, ty, tx);
      __syncthreads();
    }
    const float invN = 1.0f / 4096.0f;
#pragma unroll
    for (int i = 0; i < 4; ++i) {
      const int o = m0 + (ty << 2) + i;
      const float sc = bn_gamma[o] * rsqrtf(bn_var[o] + BN_EPS);
      const float wgs_o = Wgs[b * 256 + o];
      const float wgb_o = wgb[o];
      __bf16 h4[4], l4[4];
#pragma unroll
      for (int j = 0; j < 4; ++j) {
        const int c = n0 + (tx << 2) + j;
        const float w = sc * ((acc[i][j] + wgs_o * vpt[c] + wgb_o * sPT[b * 256 + c]) * invN +
                              wgb_o * vpt[c]);
        const __bf16 h = (__bf16)w;
        h4[j] = h;
        l4[j] = (__bf16)(w - (float)h);
      }
      __bf16* dh = Whi + (size_t)b * 65536 + (size_t)o * 256 + n0 + (tx << 2);
      __bf16* dl = Wlo + (size_t)b * 65536 + (size_t)o * 256 + n0 + (tx << 2);
      *(bf16x4*)dh = *(bf16x4*)h4;
      *(bf16x4*)dl = *(bf16x4*)l4;
    }
  } else {
    // ---- auxB: t2 = G@vb -> mtb -> bias_out ----
    const int b = blk - 64;
    __shared__ float sm[896];
    float* vb_s = sm; float* t2_s = sm + 256; float* mtb_s = sm + 512;
    float* sgb_s = sm + 640; float* gbb_s = sm + 768;
    vb_s[t] = vb_g[t];
    if (t < 128) { sgb_s[t] = sg_g[b * 128 + t]; gbb_s[t] = g_b[t]; }
    __syncthreads();
    const float d1 = dvec[0], d2 = dvec[1 + b];
    const float* Gb = G + (size_t)b * 65536;
    {
      const float4 vv = *(const float4*)&vb_s[lane * 4];
      for (int o = wave; o < 256; o += 4) {
        const float4 r = *(const float4*)(Gb + (size_t)o * 256 + lane * 4);
        float v = fmaf(r.x, vv.x, fmaf(r.y, vv.y, fmaf(r.z, vv.z, r.w * vv.w)));
        v = wave_reduce(v);
        if (lane == 0) t2_s[o] = v;
      }
    }
    __syncthreads();
    {
      const float4 tv = *(const float4*)&t2_s[lane * 4];
      for (int i = wave; i < 128; i += 4) {
        const float4 r = *(const float4*)(g_w + (size_t)i * 256 + lane * 4);
        float v = fmaf(r.x, tv.x, fmaf(r.y, tv.y, fmaf(r.z, tv.z, r.w * tv.w)));
        v = wave_reduce(v);
        if (lane == 0) mtb_s[i] = v + sgb_s[i] * d1 + gbb_s[i] * (d2 + 4096.0f * d1);
      }
    }
    __syncthreads();
    {
      const float2 mv = *(const float2*)&mtb_s[lane * 2];
      for (int o = wave; o < 256; o += 4) {
        const float2 r = *(const float2*)(W_w + (size_t)o * 128 + lane * 2);
        float v = fmaf(r.x, mv.x, r.y * mv.y);
        v = wave_reduce(v);
        if (lane == 0) {
          const float bias_full = v * (1.0f / 4096.0f);
          const float sc = bn_gamma[o] * rsqrtf(bn_var[o] + BN_EPS);
          bias_out[b * 256 + o] = sc * (bias_full - bn_mean[o]) + bn_beta[o];
        }
      }
    }
  }
}

// ================= out[b] = W_out[b] @ a[b] + bias (MFMA, 32-wide n-tiles) =======
// grid (128, 4, 4), block 256 (4 waves): 2048 blocks -> full occupancy budget
__global__ __launch_bounds__(256) void out_mfma_kernel(const __bf16* __restrict__ Whi,
                                                       const __bf16* __restrict__ Wlo,
                                                       const __bf16* __restrict__ at,
                                                       const float* __restrict__ bias_out,
                                                       float* __restrict__ out) {
  const int nt = blockIdx.x, mt = blockIdx.y, b = blockIdx.z;
  const int wave = threadIdx.x >> 6, lane = threadIdx.x & 63;
  const int m = lane & 15, q = lane >> 4;
  const int o = mt * 64 + wave * 16 + m;
  const __bf16* wh = Whi + (size_t)b * 65536 + (size_t)o * 256;
  const __bf16* wl = Wlo + (size_t)b * 65536 + (size_t)o * 256;
  const __bf16* atb = at + ((size_t)b * NSP + nt * 32) * CCH;
  f32x4 acc[2] = {};
#pragma unroll
  for (int ks = 0; ks < 8; ++ks) {
    const int k = ks * 32 + q * 8;
    const bf16x8 ah = *(const bf16x8*)(wh + k);
    const bf16x8 al = *(const bf16x8*)(wl + k);
#pragma unroll
    for (int t4 = 0; t4 < 2; ++t4) {
      const bf16x8 bh = *(const bf16x8*)(atb + (size_t)(t4 * 16 + m) * 256 + k);
      acc[t4] = __builtin_amdgcn_mfma_f32_16x16x32_bf16(ah, bh, acc[t4], 0, 0, 0);
      acc[t4] = __builtin_amdgcn_mfma_f32_16x16x32_bf16(al, bh, acc[t4], 0, 0, 0);
    }
  }
  float* ob = out + (size_t)b * CCH * NSP;
#pragma unroll
  for (int r = 0; r < 4; ++r) {
    const int orow = mt * 64 + wave * 16 + q * 4 + r;
    const float bo = bias_out[b * 256 + orow];
#pragma unroll
    for (int t4 = 0; t4 < 2; ++t4)
      ob[(size_t)orow * NSP + nt * 32 + t4 * 16 + m] = acc[t4][r] + bo;
  }
}

extern "C" void kernel_launch(void* const* d_in, const int* in_sizes, int n_in,
                              void* d_out, int out_size, void* d_ws, size_t ws_size,
                              hipStream_t stream) {
  (void)in_sizes; (void)n_in; (void)out_size; (void)ws_size;
  const float* a       = (const float*)d_in[0];
  const float* bI      = (const float*)d_in[1];
  const float* theta_w = (const float*)d_in[2];
  const float* theta_b = (const float*)d_in[3];
  const float* phi_w   = (const float*)d_in[4];
  const float* phi_b   = (const float*)d_in[5];
  const float* g_w     = (const float*)d_in[6];
  const float* g_b     = (const float*)d_in[7];
  const float* W_w     = (const float*)d_in[8];
  const float* bn_gamma= (const float*)d_in[9];
  const float* bn_beta = (const float*)d_in[10];
  const float* bn_mean = (const float*)d_in[11];
  const float* bn_var  = (const float*)d_in[12];
  float* out = (float*)d_out;
  float* ws  = (float*)d_ws;

  // fp32 region (float offsets)
  float* G        = ws;                  // 262144
  float* srow     = ws + 262144;         // 1024
  float* Wg       = ws + 263168;         // 65536
  float* PT       = ws + 328704;         // 65536
  float* T1       = ws + 394240;         // 262144
  float* bias_out = ws + 656384;         // 1024
  float* Wgs      = ws + 657408;         // 1024
  float* sPTv     = ws + 658432;         // 1024
  float* wgb      = ws + 659456;         // 256
  float* vpt      = ws + 659712;         // 256
  float* vb_g     = ws + 659968;         // 256
  float* sg_g     = ws + 660224;         // 512
  float* dvec     = ws + 660736;         // 8
  // bf16 region (no aliasing; ws is ~256 MiB)
  __bf16* bhi = (__bf16*)(ws + 661504);      // 8 MB
  __bf16* blo = (__bf16*)(ws + 2758656);     // 8 MB
  __bf16* Whi = (__bf16*)(ws + 4855808);     // 0.5 MB
  __bf16* Wlo = (__bf16*)(ws + 4986880);     // 0.5 MB
  __bf16* at  = (__bf16*)(ws + 5117952);     // 8 MB (end ~28.9 MB)

  hipMemsetAsync(G, 0, 262144 * sizeof(float), stream);  // G (atomics)

  setup_kernel<<<dim3(2080), dim3(256), 0, stream>>>(bI, bhi, blo, srow, W_w, g_w, phi_w,
                                                     theta_w, Wg, PT, a, at);
  gram_aux_kernel<<<dim3(2053), dim3(256), 0, stream>>>(bhi, blo, G, srow, W_w, g_w,
                                                        phi_w, theta_w, theta_b, phi_b,
                                                        g_b, Wgs, sPTv, wgb, vpt, vb_g,
                                                        sg_g, dvec);
  chainA_kernel<<<dim3(4, 4, 4), dim3(16, 16), 0, stream>>>(Wg, G, T1);
  chainB_aux_kernel<<<dim3(68), dim3(256), 0, stream>>>(T1, PT, Wgs, sPTv, wgb, vpt,
                                                        G, vb_g, sg_g, dvec, g_w, g_b,
                                                        W_w, bn_gamma, bn_beta, bn_mean,
                                                        bn_var, Whi, Wlo, bias_out);
  out_mfma_kernel<<<dim3(128, 4, 4), dim3(256), 0, stream>>>(Whi, Wlo, at, bias_out, out);
}

// Round 5
// 246.335 us; speedup vs baseline: 1.3210x; 1.3210x over previous
//
#include <hip/hip_runtime.h>
#include <hip/hip_bf16.h>

#define NSP 4096   // H*W
#define CCH 256    // C
#define CIN 128    // Ci
#define BN_EPS 1e-5f

typedef __bf16 bf16x8 __attribute__((ext_vector_type(8)));
typedef __bf16 bf16x4 __attribute__((ext_vector_type(4)));
typedef float f32x4 __attribute__((ext_vector_type(4)));

// ================= fp32 tile helpers (prep/chainA/chainB) ========================

__device__ __forceinline__ float4 fetch_tr(const float* __restrict__ A, int lda, int m0,
                                           int k0, int tid) {
  const int r = tid >> 2, kq = (tid & 3) << 2;
  return *(const float4*)(A + (size_t)(m0 + r) * lda + k0 + kq);
}
__device__ __forceinline__ void stash_tr(float (*As)[68], float4 v, int tid) {
  const int r = tid >> 2, kq = (tid & 3) << 2;
  As[kq + 0][r] = v.x; As[kq + 1][r] = v.y; As[kq + 2][r] = v.z; As[kq + 3][r] = v.w;
}
__device__ __forceinline__ float4 fetch_dir(const float* __restrict__ B, int ldb, int k0,
                                            int n0, int tid) {
  const int kr = tid >> 4, nq = (tid & 15) << 2;
  return *(const float4*)(B + (size_t)(k0 + kr) * ldb + n0 + nq);
}
__device__ __forceinline__ void stash_dir(float (*Bs)[68], float4 v, int tid) {
  const int kr = tid >> 4, nq = (tid & 15) << 2;
  *(float4*)(&Bs[kr][nq]) = v;
}

__device__ __forceinline__ void mm16(const float (*As)[68], const float (*Bs)[68],
                                     float acc[4][4], int ty, int tx) {
#pragma unroll
  for (int kk = 0; kk < 16; ++kk) {
    const float4 av = *(const float4*)(&As[kk][ty << 2]);
    const float4 bv = *(const float4*)(&Bs[kk][tx << 2]);
    const float ar[4] = {av.x, av.y, av.z, av.w};
    const float br[4] = {bv.x, bv.y, bv.z, bv.w};
#pragma unroll
    for (int i = 0; i < 4; ++i)
#pragma unroll
      for (int j = 0; j < 4; ++j) acc[i][j] += ar[i] * br[j];
  }
}

__device__ __forceinline__ void store_tile(float* __restrict__ C, int ldc, int m0, int n0,
                                           const float acc[4][4], int ty, int tx) {
#pragma unroll
  for (int i = 0; i < 4; ++i) {
    const float4 v = make_float4(acc[i][0], acc[i][1], acc[i][2], acc[i][3]);
    *(float4*)(C + (size_t)(m0 + (ty << 2) + i) * ldc + n0 + (tx << 2)) = v;
  }
}

__device__ __forceinline__ float wave_reduce(float v) {
#pragma unroll
  for (int off = 32; off; off >>= 1) v += __shfl_down(v, off);
  return v;  // valid in lane 0
}

// ================= setup: cast_b (0..1023) + prep (1024..1055) + cast_a (1056..2079)
__global__ __launch_bounds__(256) void setup_kernel(
    const float* __restrict__ bin, __bf16* __restrict__ bhi, __bf16* __restrict__ blo,
    float* __restrict__ srow, const float* __restrict__ W_w, const float* __restrict__ g_w,
    const float* __restrict__ phi_w, const float* __restrict__ theta_w,
    float* __restrict__ Wg, float* __restrict__ PT,
    const float* __restrict__ a, __bf16* __restrict__ at) {
  __shared__ float smem[64 * 68];
  const int idx = blockIdx.x;
  const int t = threadIdx.x;
  if (idx < 1024) {
    // ---- cast b row -> bf16 hi/lo + exact fp32 row sum ----
    const int row = idx;
    const float* src = bin + (size_t)row * NSP + t * 16;
    float sum = 0.f;
    __bf16 hi[16], lo[16];
#pragma unroll
    for (int i = 0; i < 4; ++i) {
      const float4 v = *(const float4*)(src + i * 4);
      const float vv[4] = {v.x, v.y, v.z, v.w};
#pragma unroll
      for (int j = 0; j < 4; ++j) {
        const float x = vv[j];
        sum += x;
        const __bf16 h = (__bf16)x;
        hi[i * 4 + j] = h;
        lo[i * 4 + j] = (__bf16)(x - (float)h);
      }
    }
    __bf16* dh = bhi + (size_t)row * NSP + t * 16;
    __bf16* dl = blo + (size_t)row * NSP + t * 16;
    *(bf16x8*)dh = *(bf16x8*)&hi[0];
    *(bf16x8*)(dh + 8) = *(bf16x8*)&hi[8];
    *(bf16x8*)dl = *(bf16x8*)&lo[0];
    *(bf16x8*)(dl + 8) = *(bf16x8*)&lo[8];
#pragma unroll
    for (int off = 32; off; off >>= 1) sum += __shfl_down(sum, off);
    if ((t & 63) == 0) smem[t >> 6] = sum;
    __syncthreads();
    if (t == 0) srow[row] = smem[0] + smem[1] + smem[2] + smem[3];
  } else if (idx < 1056) {
    // ---- prep: Wg = W_w @ g_w (z=0) ; PT = phi_w^T @ theta_w (z=1) ----
    const int p = idx - 1024;
    const int zsel = p >> 4, rem = p & 15;
    const int m0 = (rem >> 2) * 64, n0 = (rem & 3) * 64;
    float (*As)[68] = (float(*)[68])smem;
    float (*Bs)[68] = (float(*)[68])(smem + 16 * 68);
    const int ty = t >> 4, tx = t & 15;
    float acc[4][4] = {};
    if (zsel == 0) {
      float4 ar = fetch_tr(W_w, CIN, m0, 0, t);
      float4 br = fetch_dir(g_w, CCH, 0, n0, t);
      for (int kt = 0; kt < 8; ++kt) {
        stash_tr(As, ar, t); stash_dir(Bs, br, t);
        __syncthreads();
        if (kt < 7) { ar = fetch_tr(W_w, CIN, m0, (kt + 1) * 16, t);
                      br = fetch_dir(g_w, CCH, (kt + 1) * 16, n0, t); }
        mm16(As, Bs, acc, ty, tx);
        __syncthreads();
      }
      store_tile(Wg, 256, m0, n0, acc, ty, tx);
    } else {
      float4 ar = fetch_dir(phi_w, CCH, 0, m0, t);
      float4 br = fetch_dir(theta_w, CCH, 0, n0, t);
      for (int kt = 0; kt < 8; ++kt) {
        stash_dir(As, ar, t); stash_dir(Bs, br, t);
        __syncthreads();
        if (kt < 7) { ar = fetch_dir(phi_w, CCH, (kt + 1) * 16, m0, t);
                      br = fetch_dir(theta_w, CCH, (kt + 1) * 16, n0, t); }
        mm16(As, Bs, acc, ty, tx);
        __syncthreads();
      }
      store_tile(PT, 256, m0, n0, acc, ty, tx);
    }
  } else {
    // ---- cast a -> bf16 transposed: at[b][n][c] ----
    const int p = idx - 1056;
    const int n0 = (p & 63) * 64, c0 = ((p >> 6) & 3) * 64, b = p >> 8;
    float (*tile)[68] = (float(*)[68])smem;
    const int cr = t >> 4, nq = (t & 15) << 2;
    const float* src = a + ((size_t)(b * CCH + c0)) * NSP + n0;
#pragma unroll
    for (int s = 0; s < 4; ++s) {
      const float4 v = *(const float4*)(src + (size_t)(cr + s * 16) * NSP + nq);
      *(float4*)&tile[cr + s * 16][nq] = v;
    }
    __syncthreads();
    const int n = t >> 2, cq = (t & 3) << 4;
    __bf16 outv[16];
#pragma unroll
    for (int i = 0; i < 16; ++i) outv[i] = (__bf16)tile[cq + i][n];
    __bf16* dst = at + ((size_t)(b * NSP + n0 + n)) * CCH + c0 + cq;
    *(bf16x8*)dst = *(bf16x8*)&outv[0];
    *(bf16x8*)(dst + 8) = *(bf16x8*)&outv[8];
  }
}

// ================= gram partials: Gpart[kc][b] = B_b[:,kc] B_b[:,kc]^T ===========
// grid (4 jt, 4 it, batch*16+kc), block 256 (4 waves). K=256/block. Plain stores.
__global__ __launch_bounds__(256) void gram_mfma_kernel(const __bf16* __restrict__ bhi,
                                                        const __bf16* __restrict__ blo,
                                                        float* __restrict__ Gpart) {
  const int jt = blockIdx.x, it = blockIdx.y;
  const int batch = blockIdx.z >> 4, kc = blockIdx.z & 15;
  const int wave = threadIdx.x >> 6, lane = threadIdx.x & 63;
  const int m = lane & 15, q = lane >> 4;
  const size_t base = (size_t)batch * CCH * NSP;
  const size_t arow = base + (size_t)(it * 64 + wave * 16 + m) * NSP + kc * 256 + q * 8;
  const size_t brow = base + (size_t)(jt * 64 + m) * NSP + kc * 256 + q * 8;
  f32x4 acc[4] = {};
#pragma unroll
  for (int ks = 0; ks < 8; ++ks) {
    const int k = ks * 32;
    const bf16x8 ah = *(const bf16x8*)(bhi + arow + k);
    const bf16x8 al = *(const bf16x8*)(blo + arow + k);
#pragma unroll
    for (int t4 = 0; t4 < 4; ++t4) {
      const size_t boff = brow + (size_t)t4 * 16 * NSP + k;
      const bf16x8 bh = *(const bf16x8*)(bhi + boff);
      const bf16x8 bl = *(const bf16x8*)(blo + boff);
      acc[t4] = __builtin_amdgcn_mfma_f32_16x16x32_bf16(ah, bh, acc[t4], 0, 0, 0);
      acc[t4] = __builtin_amdgcn_mfma_f32_16x16x32_bf16(ah, bl, acc[t4], 0, 0, 0);
      acc[t4] = __builtin_amdgcn_mfma_f32_16x16x32_bf16(al, bh, acc[t4], 0, 0, 0);
    }
  }
  float* Gp = Gpart + ((size_t)(kc * 4 + batch)) * 65536;
#pragma unroll
  for (int t4 = 0; t4 < 4; ++t4)
#pragma unroll
    for (int r = 0; r < 4; ++r)
      Gp[(size_t)(it * 64 + wave * 16 + q * 4 + r) * 256 + jt * 64 + t4 * 16 + m] =
          acc[t4][r];
}

// ================= reduce (blocks 0..63) + auxA (64..68), 1024 threads ===========
__global__ __launch_bounds__(1024) void reduce_auxA_kernel(
    const float* __restrict__ Gpart, float* __restrict__ G,
    const float* __restrict__ srow, const float* __restrict__ W_w,
    const float* __restrict__ g_w, const float* __restrict__ phi_w,
    const float* __restrict__ theta_w, const float* __restrict__ theta_b,
    const float* __restrict__ phi_b, const float* __restrict__ g_b,
    float* __restrict__ Wgs, float* __restrict__ sPTv, float* __restrict__ wgb,
    float* __restrict__ vpt, float* __restrict__ vb_g, float* __restrict__ sg_g,
    float* __restrict__ dvec) {
  const int blkid = blockIdx.x;
  const int t = threadIdx.x;
  const int wave = t >> 6, lane = t & 63;
  if (blkid < 64) {
    // ---- G = sum over 16 K-chunk partials (1 float4 per thread) ----
    const int v = blkid * 1024 + t;       // float4 index, 0..65535
    const int o = v << 2;                 // float offset
    const int batch = o >> 16, i = o & 65535;
    f32x4 s = {};
#pragma unroll
    for (int p = 0; p < 16; ++p)
      s += *(const f32x4*)(Gpart + ((size_t)((p << 2) + batch) << 16) + i);
    *(f32x4*)(G + ((size_t)batch << 16) + i) = s;
  } else if (blkid < 68) {
    // ---- auxA per-batch: sp = phi_w@s, sg = g_w@s -> Wgs, sPTv, d2, sg_g ----
    const int b = blkid - 64;
    __shared__ float s_s[256], sp_s[128], sg_s[128];
    if (t < 256) s_s[t] = srow[b * 256 + t];
    __syncthreads();
    const float4 sv = *(const float4*)&s_s[lane * 4];
    for (int j = wave; j < 256; j += 16) {
      const float* row = (j < 128) ? (phi_w + (size_t)j * 256)
                                   : (g_w + (size_t)(j - 128) * 256);
      const float4 r = *(const float4*)(row + lane * 4);
      float v = fmaf(r.x, sv.x, fmaf(r.y, sv.y, fmaf(r.z, sv.z, r.w * sv.w)));
      v = wave_reduce(v);
      if (lane == 0) { if (j < 128) sp_s[j] = v; else sg_s[j - 128] = v; }
    }
    __syncthreads();
    if (t < 128) sg_g[b * 128 + t] = sg_s[t];
    if (t < 256) {
      // sPTv[c] = sum_i sp[i]*theta_w[i][c] (coalesced cols)
      float acc = 0.f;
#pragma unroll 8
      for (int i = 0; i < 128; ++i) acc += sp_s[i] * theta_w[(size_t)i * 256 + t];
      sPTv[b * 256 + t] = acc;
      if (wave == 0) {  // d2 = sp . theta_b
        float pv = sp_s[lane] * theta_b[lane] + sp_s[lane + 64] * theta_b[lane + 64];
        pv = wave_reduce(pv);
        if (lane == 0) dvec[1 + b] = pv;
      }
    } else {
      // Wgs[o] = W_w[o] . sg  (waves 4..15)
      const float2 mv = *(const float2*)&sg_s[lane * 2];
      for (int o = wave - 4; o < 256; o += 12) {
        const float2 r = *(const float2*)(W_w + (size_t)o * 128 + lane * 2);
        float v = fmaf(r.x, mv.x, r.y * mv.y);
        v = wave_reduce(v);
        if (lane == 0) Wgs[b * 256 + o] = v;
      }
    }
  } else {
    // ---- auxA global: vpt, vb, wgb, d1 ----
    __shared__ float pb_s[128], tb_s[128], gb_s[128];
    if (t < 128) { pb_s[t] = phi_b[t]; tb_s[t] = theta_b[t]; gb_s[t] = g_b[t]; }
    __syncthreads();
    if (t < 256) {
      // vpt[c] = sum_i phi_b[i]*theta_w[i][c]
      float acc = 0.f;
#pragma unroll 8
      for (int i = 0; i < 128; ++i) acc += pb_s[i] * theta_w[(size_t)i * 256 + t];
      vpt[t] = acc;
      if (wave == 0) {  // d1 = phi_b . theta_b
        float pv = pb_s[lane] * tb_s[lane] + pb_s[lane + 64] * tb_s[lane + 64];
        pv = wave_reduce(pv);
        if (lane == 0) dvec[0] = pv;
      }
    } else if (t < 512) {
      // vb[c] = sum_i phi_w[i][c]*theta_b[i]
      const int c = t - 256;
      float acc = 0.f;
#pragma unroll 8
      for (int i = 0; i < 128; ++i) acc += phi_w[(size_t)i * 256 + c] * tb_s[i];
      vb_g[c] = acc;
    } else {
      // wgb[o] = W_w[o] . g_b  (waves 8..15)
      const float2 gv = *(const float2*)&gb_s[lane * 2];
      for (int o = wave - 8; o < 256; o += 8) {
        const float2 r = *(const float2*)(W_w + (size_t)o * 128 + lane * 2);
        float v = fmaf(r.x, gv.x, r.y * gv.y);
        v = wave_reduce(v);
        if (lane == 0) wgb[o] = v;
      }
    }
  }
}

// ================= T1[b] = Wg @ G[b] (fp32 tiles, reg-prefetch) ==================
__global__ __launch_bounds__(256) void chainA_kernel(const float* __restrict__ Wg,
                                                     const float* __restrict__ G,
                                                     float* __restrict__ T1) {
  const int b = blockIdx.z;
  __shared__ float As[16][68], Bs[16][68];
  const int n0 = blockIdx.x * 64, m0 = blockIdx.y * 64;
  const int tx = threadIdx.x, ty = threadIdx.y;
  const int tid = (ty << 4) | tx;
  const float* Gb = G + (size_t)b * 65536;
  float acc[4][4] = {};
  float4 ar = fetch_tr(Wg, 256, m0, 0, tid);
  float4 br = fetch_dir(Gb, 256, 0, n0, tid);
  for (int kt = 0; kt < 16; ++kt) {
    stash_tr(As, ar, tid); stash_dir(Bs, br, tid);
    __syncthreads();
    if (kt < 15) { ar = fetch_tr(Wg, 256, m0, (kt + 1) * 16, tid);
                   br = fetch_dir(Gb, 256, (kt + 1) * 16, n0, tid); }
    mm16(As, Bs, acc, ty, tx);
    __syncthreads();
  }
  store_tile(T1 + (size_t)b * 65536, 256, m0, n0, acc, ty, tx);
}

// ================= auxB: t2 = G@vb -> mtb -> bias_out (1024 thr, 4 blocks) =======
__global__ __launch_bounds__(1024) void auxB_kernel(
    const float* __restrict__ G, const float* __restrict__ vb_g,
    const float* __restrict__ sg_g, const float* __restrict__ dvec,
    const float* __restrict__ g_w, const float* __restrict__ g_b,
    const float* __restrict__ W_w,
    const float* __restrict__ bn_gamma, const float* __restrict__ bn_beta,
    const float* __restrict__ bn_mean, const float* __restrict__ bn_var,
    float* __restrict__ bias_out) {
  const int b = blockIdx.x;
  const int t = threadIdx.x;
  const int wave = t >> 6, lane = t & 63;
  __shared__ float vb_s[256], t2_s[256], mtb_s[128], sgb_s[128], gbb_s[128];
  if (t < 256) vb_s[t] = vb_g[t];
  if (t >= 256 && t < 384) sgb_s[t - 256] = sg_g[b * 128 + (t - 256)];
  if (t >= 384 && t < 512) gbb_s[t - 384] = g_b[t - 384];
  __syncthreads();
  const float d1 = dvec[0], d2 = dvec[1 + b];
  const float* Gb = G + (size_t)b * 65536;
  {  // t2 = G @ vb : wave-dots len-256
    const float4 vv = *(const float4*)&vb_s[lane * 4];
    for (int o = wave; o < 256; o += 16) {
      const float4 r = *(const float4*)(Gb + (size_t)o * 256 + lane * 4);
      float v = fmaf(r.x, vv.x, fmaf(r.y, vv.y, fmaf(r.z, vv.z, r.w * vv.w)));
      v = wave_reduce(v);
      if (lane == 0) t2_s[o] = v;
    }
  }
  __syncthreads();
  {  // mtb[i] = g_w[i].t2 + sg[i]*d1 + g_b[i]*(d2 + 4096*d1)
    const float4 tv = *(const float4*)&t2_s[lane * 4];
    for (int i = wave; i < 128; i += 16) {
      const float4 r = *(const float4*)(g_w + (size_t)i * 256 + lane * 4);
      float v = fmaf(r.x, tv.x, fmaf(r.y, tv.y, fmaf(r.z, tv.z, r.w * tv.w)));
      v = wave_reduce(v);
      if (lane == 0) mtb_s[i] = v + sgb_s[i] * d1 + gbb_s[i] * (d2 + 4096.0f * d1);
    }
  }
  __syncthreads();
  {  // bias_out[o] = sc*( (W_w[o].mtb)/4096 - mean ) + beta
    const float2 mv = *(const float2*)&mtb_s[lane * 2];
    for (int o = wave; o < 256; o += 16) {
      const float2 r = *(const float2*)(W_w + (size_t)o * 128 + lane * 2);
      float v = fmaf(r.x, mv.x, r.y * mv.y);
      v = wave_reduce(v);
      if (lane == 0) {
        const float bias_full = v * (1.0f / 4096.0f);
        const float sc = bn_gamma[o] * rsqrtf(bn_var[o] + BN_EPS);
        bias_out[b * 256 + o] = sc * (bias_full - bn_mean[o]) + bn_beta[o];
      }
    }
  }
}

// ================= W_out[b] (bf16 hi/lo) = scale*((T1@PT + rank1)/N + rank1') ====
__global__ __launch_bounds__(256) void chainB_kernel(
    const float* __restrict__ T1, const float* __restrict__ PT,
    const float* __restrict__ Wgs, const float* __restrict__ sPT,
    const float* __restrict__ wgb, const float* __restrict__ vpt,
    const float* __restrict__ bn_gamma, const float* __restrict__ bn_var,
    __bf16* __restrict__ Whi, __bf16* __restrict__ Wlo) {
  const int b = blockIdx.z;
  __shared__ float As[16][68], Bs[16][68];
  const int n0 = blockIdx.x * 64, m0 = blockIdx.y * 64;
  const int tx = threadIdx.x, ty = threadIdx.y;
  const int tid = (ty << 4) | tx;
  const float* T1b = T1 + (size_t)b * 65536;
  float acc[4][4] = {};
  float4 ar = fetch_tr(T1b, 256, m0, 0, tid);
  float4 br = fetch_dir(PT, 256, 0, n0, tid);
  for (int kt = 0; kt < 16; ++kt) {
    stash_tr(As, ar, tid); stash_dir(Bs, br, tid);
    __syncthreads();
    if (kt < 15) { ar = fetch_tr(T1b, 256, m0, (kt + 1) * 16, tid);
                   br = fetch_dir(PT, 256, (kt + 1) * 16, n0, tid); }
    mm16(As, Bs, acc, ty, tx);
    __syncthreads();
  }
  const float invN = 1.0f / 4096.0f;
#pragma unroll
  for (int i = 0; i < 4; ++i) {
    const int o = m0 + (ty << 2) + i;
    const float sc = bn_gamma[o] * rsqrtf(bn_var[o] + BN_EPS);
    const float wgs_o = Wgs[b * 256 + o];
    const float wgb_o = wgb[o];
    __bf16 h4[4], l4[4];
#pragma unroll
    for (int j = 0; j < 4; ++j) {
      const int c = n0 + (tx << 2) + j;
      const float w = sc * ((acc[i][j] + wgs_o * vpt[c] + wgb_o * sPT[b * 256 + c]) * invN +
                            wgb_o * vpt[c]);
      const __bf16 h = (__bf16)w;
      h4[j] = h;
      l4[j] = (__bf16)(w - (float)h);
    }
    __bf16* dh = Whi + (size_t)b * 65536 + (size_t)o * 256 + n0 + (tx << 2);
    __bf16* dl = Wlo + (size_t)b * 65536 + (size_t)o * 256 + n0 + (tx << 2);
    *(bf16x4*)dh = *(bf16x4*)h4;
    *(bf16x4*)dl = *(bf16x4*)l4;
  }
}

// ================= out[b] = W_out[b] @ a[b] + bias (MFMA, 32-wide n-tiles) =======
__global__ __launch_bounds__(256) void out_mfma_kernel(const __bf16* __restrict__ Whi,
                                                       const __bf16* __restrict__ Wlo,
                                                       const __bf16* __restrict__ at,
                                                       const float* __restrict__ bias_out,
                                                       float* __restrict__ out) {
  const int nt = blockIdx.x, mt = blockIdx.y, b = blockIdx.z;
  const int wave = threadIdx.x >> 6, lane = threadIdx.x & 63;
  const int m = lane & 15, q = lane >> 4;
  const int o = mt * 64 + wave * 16 + m;
  const __bf16* wh = Whi + (size_t)b * 65536 + (size_t)o * 256;
  const __bf16* wl = Wlo + (size_t)b * 65536 + (size_t)o * 256;
  const __bf16* atb = at + ((size_t)b * NSP + nt * 32) * CCH;
  f32x4 acc[2] = {};
#pragma unroll
  for (int ks = 0; ks < 8; ++ks) {
    const int k = ks * 32 + q * 8;
    const bf16x8 ah = *(const bf16x8*)(wh + k);
    const bf16x8 al = *(const bf16x8*)(wl + k);
#pragma unroll
    for (int t4 = 0; t4 < 2; ++t4) {
      const bf16x8 bh = *(const bf16x8*)(atb + (size_t)(t4 * 16 + m) * 256 + k);
      acc[t4] = __builtin_amdgcn_mfma_f32_16x16x32_bf16(ah, bh, acc[t4], 0, 0, 0);
      acc[t4] = __builtin_amdgcn_mfma_f32_16x16x32_bf16(al, bh, acc[t4], 0, 0, 0);
    }
  }
  float* ob = out + (size_t)b * CCH * NSP;
#pragma unroll
  for (int r = 0; r < 4; ++r) {
    const int orow = mt * 64 + wave * 16 + q * 4 + r;
    const float bo = bias_out[b * 256 + orow];
#pragma unroll
    for (int t4 = 0; t4 < 2; ++t4)
      ob[(size_t)orow * NSP + nt * 32 + t4 * 16 + m] = acc[t4][r] + bo;
  }
}

extern "C" void kernel_launch(void* const* d_in, const int* in_sizes, int n_in,
                              void* d_out, int out_size, void* d_ws, size_t ws_size,
                              hipStream_t stream) {
  (void)in_sizes; (void)n_in; (void)out_size; (void)ws_size;
  const float* a       = (const float*)d_in[0];
  const float* bI      = (const float*)d_in[1];
  const float* theta_w = (const float*)d_in[2];
  const float* theta_b = (const float*)d_in[3];
  const float* phi_w   = (const float*)d_in[4];
  const float* phi_b   = (const float*)d_in[5];
  const float* g_w     = (const float*)d_in[6];
  const float* g_b     = (const float*)d_in[7];
  const float* W_w     = (const float*)d_in[8];
  const float* bn_gamma= (const float*)d_in[9];
  const float* bn_beta = (const float*)d_in[10];
  const float* bn_mean = (const float*)d_in[11];
  const float* bn_var  = (const float*)d_in[12];
  float* out = (float*)d_out;
  float* ws  = (float*)d_ws;

  // fp32 region (float offsets)
  float* Gpart    = ws;                  // 16*4*65536 = 4194304 (16 MB)
  float* G        = ws + 4194304;        // 262144
  float* srow     = ws + 4456448;        // 1024
  float* Wg       = ws + 4457472;        // 65536
  float* PT       = ws + 4523008;        // 65536
  float* T1       = ws + 4588544;        // 262144
  float* bias_out = ws + 4850688;        // 1024
  float* Wgs      = ws + 4851712;        // 1024
  float* sPTv     = ws + 4852736;        // 1024
  float* wgb      = ws + 4853760;        // 256
  float* vpt      = ws + 4854016;        // 256
  float* vb_g     = ws + 4854272;        // 256
  float* sg_g     = ws + 4854528;        // 512
  float* dvec     = ws + 4855040;        // 8
  // bf16 region
  __bf16* bhi = (__bf16*)(ws + 4855552);     // 8 MB
  __bf16* blo = (__bf16*)(ws + 6952704);     // 8 MB
  __bf16* Whi = (__bf16*)(ws + 9049856);     // 0.5 MB
  __bf16* Wlo = (__bf16*)(ws + 9180928);     // 0.5 MB
  __bf16* at  = (__bf16*)(ws + 9312000);     // 8 MB (end ~45.6 MB)

  setup_kernel<<<dim3(2080), dim3(256), 0, stream>>>(bI, bhi, blo, srow, W_w, g_w, phi_w,
                                                     theta_w, Wg, PT, a, at);
  gram_mfma_kernel<<<dim3(4, 4, 64), dim3(256), 0, stream>>>(bhi, blo, Gpart);
  reduce_auxA_kernel<<<dim3(69), dim3(1024), 0, stream>>>(Gpart, G, srow, W_w, g_w,
                                                          phi_w, theta_w, theta_b, phi_b,
                                                          g_b, Wgs, sPTv, wgb, vpt, vb_g,
                                                          sg_g, dvec);
  chainA_kernel<<<dim3(4, 4, 4), dim3(16, 16), 0, stream>>>(Wg, G, T1);
  auxB_kernel<<<dim3(4), dim3(1024), 0, stream>>>(G, vb_g, sg_g, dvec, g_w, g_b, W_w,
                                                  bn_gamma, bn_beta, bn_mean, bn_var,
                                                  bias_out);
  chainB_kernel<<<dim3(4, 4, 4), dim3(16, 16), 0, stream>>>(T1, PT, Wgs, sPTv, wgb, vpt,
                                                            bn_gamma, bn_var, Whi, Wlo);
  out_mfma_kernel<<<dim3(128, 4, 4), dim3(256), 0, stream>>>(Whi, Wlo, at, bias_out, out);
}